// Round 9
// baseline (229.522 us; speedup 1.0000x reference)
//
#include <hip/hip_runtime.h>
#include <math.h>

// Problem constants (fixed by reference): IN=512, H=4, C=32, H*C=128.
constexpr int IN_F = 512;
constexpr int NH   = 4;
constexpr int CH   = 32;
constexpr int HC   = 128;   // NH*CH
constexpr int SCAN_ELEMS = 1024;

typedef short  short8 __attribute__((ext_vector_type(8)));
typedef float  f32x4  __attribute__((ext_vector_type(4)));

typedef __attribute__((address_space(3))) void as3_void;
typedef __attribute__((address_space(1))) void as1_void;
#define GLOAD_LDS16(g, l) \
    __builtin_amdgcn_global_load_lds((const as1_void*)(g), (as3_void*)(l), 16, 0, 0)

__device__ __forceinline__ unsigned short f2bf(float f) {
    unsigned u = __float_as_uint(f);
    unsigned r = (u + 0x7fff + ((u >> 16) & 1)) >> 16;   // RNE
    return (unsigned short)r;
}
__device__ __forceinline__ float bf2f(unsigned short b) {
    return __uint_as_float(((unsigned)b) << 16);
}
// unpack packed bf16x2 (u32) -> two floats
__device__ __forceinline__ float bfu_lo(unsigned u) {
    return __uint_as_float(u << 16);
}
__device__ __forceinline__ float bfu_hi(unsigned u) {
    return __uint_as_float(u & 0xffff0000u);
}
__device__ __forceinline__ float sig_exp(float x) {
    return __expf(1.0f / (1.0f + __expf(-x)));
}

// ---------------------------------------------------------------------------
// W[512x128] fp32 -> Wt[128x512] bf16 (transposed).
// ---------------------------------------------------------------------------
__global__ void prep_w(const float* __restrict__ W,
                       unsigned short* __restrict__ Wt) {
    int t = blockIdx.x * blockDim.x + threadIdx.x;
    if (t >= IN_F * HC) return;
    int k = t >> 7, n = t & 127;
    Wt[(size_t)n * IN_F + k] = f2bf(W[t]);
}

// ---------------------------------------------------------------------------
// h fp32 [M*512] -> bf16 [Mpad*512], zero-padded rows.
// ---------------------------------------------------------------------------
__global__ void cvt_h(const float* __restrict__ h, unsigned* __restrict__ hb,
                      int n_elems, int n_pad) {
    int i8 = (blockIdx.x * blockDim.x + threadIdx.x) * 8;
    if (i8 >= n_pad) return;
    uint4 o;
    if (i8 < n_elems) {
        float4 v0 = *(const float4*)(h + i8);
        float4 v1 = *(const float4*)(h + i8 + 4);
        o.x = (unsigned)f2bf(v0.x) | ((unsigned)f2bf(v0.y) << 16);
        o.y = (unsigned)f2bf(v0.z) | ((unsigned)f2bf(v0.w) << 16);
        o.z = (unsigned)f2bf(v1.x) | ((unsigned)f2bf(v1.y) << 16);
        o.w = (unsigned)f2bf(v1.z) | ((unsigned)f2bf(v1.w) << 16);
    } else {
        o = make_uint4(0, 0, 0, 0);
    }
    *(uint4*)(hb + i8 / 2) = o;
}

// ---------------------------------------------------------------------------
// LDS fragment reader: rows of 128 B (64 bf16), XOR-swizzled 16B chunks:
// byte = row*128 + (b ^ ((row&7)<<4)).
// ---------------------------------------------------------------------------
__device__ __forceinline__ short8 frag_read(const char* tile, int row, int kb) {
    const int sw = (row & 7) << 4;
    const int b0 = row * 128 + ((kb)      ^ sw);
    const int b1 = row * 128 + ((kb + 32) ^ sw);
    ushort4 lo = *(const ushort4*)(tile + b0);
    ushort4 hi = *(const ushort4*)(tile + b1);
    short8 f;
    f[0] = (short)lo.x; f[1] = (short)lo.y; f[2] = (short)lo.z; f[3] = (short)lo.w;
    f[4] = (short)hi.x; f[5] = (short)hi.y; f[6] = (short)hi.z; f[7] = (short)hi.w;
    return f;
}

// ---------------------------------------------------------------------------
// GEMM: htb[M x 128] (bf16) = hbf[Mpad x 512] @ Wt^T, m97-style staging.
// BM=64, BN=128, BK=64. 256 threads = 4 waves (2x2), wave tile 32x64.
// ---------------------------------------------------------------------------
__global__ __launch_bounds__(256) void gemm_bf16(
        const unsigned short* __restrict__ Abf,   // [Mpad][512]
        const unsigned short* __restrict__ Wt,    // [128][512]
        unsigned short* __restrict__ C16, int M) {
    __shared__ __align__(16) char smem[24576];
    char* As = smem;          // 8 KB
    char* Bs = smem + 8192;   // 16 KB

    const int tid  = threadIdx.x;
    const int lane = tid & 63;
    const int wave = tid >> 6;
    const int wr  = wave & 1;       // row half (32 rows)
    const int wcq = wave >> 1;      // col half (64 cols)
    const int brow = blockIdx.x * 64;
    const int lr = lane & 15;
    const int lg = lane >> 4;

    f32x4 acc[2][4];
#pragma unroll
    for (int i = 0; i < 2; ++i)
#pragma unroll
        for (int j = 0; j < 4; ++j)
            acc[i][j] = f32x4{0.f, 0.f, 0.f, 0.f};

    for (int kc = 0; kc < IN_F; kc += 64) {
        __syncthreads();   // prior compute done before overwrite
        // ---- stage A (2 chunks/thread), pre-swizzled global source ----
#pragma unroll
        for (int p = 0; p < 2; ++p) {
            const int c = tid + 256 * p;
            const int r = c >> 3, j = c & 7;
            const unsigned short* src = Abf + (size_t)(brow + r) * IN_F + kc
                                        + ((j ^ (r & 7)) << 3);
            GLOAD_LDS16(src, As + wave * 1024 + p * 4096);
        }
        // ---- stage B (4 chunks/thread) ----
#pragma unroll
        for (int p = 0; p < 4; ++p) {
            const int c = tid + 256 * p;
            const int n = c >> 3, j = c & 7;
            const unsigned short* src = Wt + (size_t)n * IN_F + kc
                                        + ((j ^ (n & 7)) << 3);
            GLOAD_LDS16(src, Bs + wave * 1024 + p * 4096);
        }
        __syncthreads();   // drains vmcnt before ds_read

        // ---- compute: 2 k-steps of 32 ----
#pragma unroll
        for (int ks = 0; ks < 2; ++ks) {
            const int kb = ks * 64 + 8 * lg;
            short8 af[2];
#pragma unroll
            for (int mi = 0; mi < 2; ++mi)
                af[mi] = frag_read(As, wr * 32 + mi * 16 + lr, kb);
            short8 bf[4];
#pragma unroll
            for (int ni = 0; ni < 4; ++ni)
                bf[ni] = frag_read(Bs, wcq * 64 + ni * 16 + lr, kb);
#pragma unroll
            for (int mi = 0; mi < 2; ++mi)
#pragma unroll
                for (int ni = 0; ni < 4; ++ni)
                    acc[mi][ni] = __builtin_amdgcn_mfma_f32_16x16x32_bf16(
                        af[mi], bf[ni], acc[mi][ni], 0, 0, 0);
        }
    }

    // ---- epilogue: bf16 store; C/D layout col=lane&15, row=4*(lane>>4)+reg
#pragma unroll
    for (int mi = 0; mi < 2; ++mi) {
        const int r0 = brow + wr * 32 + mi * 16 + 4 * lg;
#pragma unroll
        for (int ni = 0; ni < 4; ++ni) {
            const int c0 = wcq * 64 + ni * 16 + lr;
#pragma unroll
            for (int j = 0; j < 4; ++j) {
                const int r = r0 + j;
                if (r < M) C16[(size_t)r * HC + c0] = f2bf(acc[mi][ni][j]);
            }
        }
    }
}

// ---------------------------------------------------------------------------
// Per-(node,head) attention logits from bf16 ht.
// ---------------------------------------------------------------------------
__global__ void node_logits(const unsigned* __restrict__ htb32,
                            const float* __restrict__ att_src,
                            const float* __restrict__ att_dst,
                            float* __restrict__ a_s, float* __restrict__ a_d,
                            int N) {
    int t = blockIdx.x * blockDim.x + threadIdx.x;
    if (t >= N * NH) return;
    const int n  = t >> 2;
    const int hh = t & 3;
    const unsigned* p = htb32 + (size_t)n * (HC / 2) + hh * (CH / 2);
    const float* ps = att_src + hh * CH;
    const float* pd = att_dst + hh * CH;
    float s = 0.f, d = 0.f;
#pragma unroll
    for (int i = 0; i < CH / 2; i += 2) {
        uint2 u = *(const uint2*)(p + i);
        float4 as = *(const float4*)(ps + 2 * i);
        float4 ad = *(const float4*)(pd + 2 * i);
        float v0 = bfu_lo(u.x), v1 = bfu_hi(u.x);
        float v2 = bfu_lo(u.y), v3 = bfu_hi(u.y);
        s += v0 * as.x + v1 * as.y + v2 * as.z + v3 * as.w;
        d += v0 * ad.x + v1 * ad.y + v2 * ad.z + v3 * ad.w;
    }
    a_s[t] = s;
    a_d[t] = d;
}

// ---------------------------------------------------------------------------
// CSR build.
// ---------------------------------------------------------------------------
__global__ void init_counts(int* __restrict__ counts, int N) {
    int i = blockIdx.x * blockDim.x + threadIdx.x;
    if (i < N) counts[i] = 1;   // self loop
}

__global__ void hist_edges(const int* __restrict__ dst, int* __restrict__ counts, int E) {
    int e = blockIdx.x * blockDim.x + threadIdx.x;
    if (e < E) atomicAdd(&counts[dst[e]], 1);
}

__global__ __launch_bounds__(256) void scan1(const int* __restrict__ counts,
                                             int* __restrict__ row_start,
                                             int* __restrict__ blk_sums, int N) {
    __shared__ int sh[256];
    const int b = blockIdx.x, t = threadIdx.x;
    const int base = b * SCAN_ELEMS + t * 4;
    int v[4], s = 0;
#pragma unroll
    for (int i = 0; i < 4; ++i) {
        v[i] = (base + i < N) ? counts[base + i] : 0;
        s += v[i];
    }
    sh[t] = s;
    __syncthreads();
    for (int off = 1; off < 256; off <<= 1) {
        int x = (t >= off) ? sh[t - off] : 0;
        __syncthreads();
        sh[t] += x;
        __syncthreads();
    }
    int run = sh[t] - s;
#pragma unroll
    for (int i = 0; i < 4; ++i) {
        if (base + i < N) row_start[base + i] = run;
        run += v[i];
    }
    if (t == 255) blk_sums[b] = sh[255];
}

__global__ void scan2(int* __restrict__ blk_sums, int nb) {
    if (threadIdx.x == 0 && blockIdx.x == 0) {
        int acc = 0;
        for (int i = 0; i < nb; ++i) { int v = blk_sums[i]; blk_sums[i] = acc; acc += v; }
    }
}

__global__ void scan3(int* __restrict__ row_start, int* __restrict__ cursor,
                      const int* __restrict__ blk_sums, int N, int total) {
    int i = blockIdx.x * blockDim.x + threadIdx.x;
    if (i < N) {
        int v = row_start[i] + blk_sums[i / SCAN_ELEMS];
        row_start[i] = v;
        cursor[i] = v;
    }
    if (i == 0) row_start[N] = total;
}

// Scatter (src,dst) pairs into CSR slot order (packed 8B store).
__global__ void scatter_edges(const int* __restrict__ src, const int* __restrict__ dst,
                              int* __restrict__ cursor, int2* __restrict__ esd,
                              int E, int N) {
    int e = blockIdx.x * blockDim.x + threadIdx.x;
    if (e >= E + N) return;
    const int s = (e < E) ? src[e] : (e - E);
    const int d = (e < E) ? dst[e] : (e - E);
    int pos = atomicAdd(&cursor[d], 1);
    esd[pos] = make_int2(s, d);
}

// ---------------------------------------------------------------------------
// Per-CSR-slot edge exponentials: exf[j][h] = exp(sigmoid(a_s[s,h]+a_d[d,h])).
// Computed ONCE per (edge, head) — removes 16x-redundant trans ops from the
// aggregate wave loop and converts the a_s gather to a streaming pattern.
// ---------------------------------------------------------------------------
__global__ void edge_exf(const int2* __restrict__ esd,
                         const float* __restrict__ a_s,
                         const float* __restrict__ a_d,
                         float4* __restrict__ exf, int TOT) {
    int j = blockIdx.x * blockDim.x + threadIdx.x;
    if (j >= TOT) return;
    const int2 sd = esd[j];
    const float4 as = *(const float4*)(a_s + (size_t)sd.x * NH);
    const float4 ad = *(const float4*)(a_d + (size_t)sd.y * NH);
    float4 r;
    r.x = sig_exp(as.x + ad.x);
    r.y = sig_exp(as.y + ad.y);
    r.z = sig_exp(as.z + ad.z);
    r.w = sig_exp(as.w + ad.w);
    exf[j] = r;
}

// ---------------------------------------------------------------------------
// Fused softmax + aggregation, one wave per dst node, bf16 ht gather,
// precomputed edge exponentials (pure FMA loop).
// Lane l: u32 = 2 channels (c2 = 2l, 2l+1), head = l>>4.
// ---------------------------------------------------------------------------
__global__ __launch_bounds__(256) void aggregate_csr(
        const int* __restrict__ row_start, const int2* __restrict__ esd,
        const float* __restrict__ exf,
        const unsigned* __restrict__ htb32, const float* __restrict__ bias,
        float* __restrict__ out, int N) {
    const int n = blockIdx.x * 4 + (threadIdx.x >> 6);
    if (n >= N) return;
    const int lane = threadIdx.x & 63;
    const int hh   = lane >> 4;
    const int c2   = lane * 2;

    const int rs = row_start[n], re = row_start[n + 1];

    float ax0 = 0.f, ay0 = 0.f, es0 = 0.f;
    float ax1 = 0.f, ay1 = 0.f, es1 = 0.f;
    int j = rs;
    for (; j + 1 < re; j += 2) {
        const int s0 = esd[j].x, s1 = esd[j + 1].x;
        const float e0 = exf[(size_t)j * NH + hh];
        const float e1 = exf[(size_t)(j + 1) * NH + hh];
        const unsigned u0 = htb32[(size_t)s0 * (HC / 2) + lane];
        const unsigned u1 = htb32[(size_t)s1 * (HC / 2) + lane];
        ax0 += e0 * bfu_lo(u0);  ay0 += e0 * bfu_hi(u0);  es0 += e0;
        ax1 += e1 * bfu_lo(u1);  ay1 += e1 * bfu_hi(u1);  es1 += e1;
    }
    if (j < re) {
        const int s0 = esd[j].x;
        const float e0 = exf[(size_t)j * NH + hh];
        const unsigned u0 = htb32[(size_t)s0 * (HC / 2) + lane];
        ax0 += e0 * bfu_lo(u0);  ay0 += e0 * bfu_hi(u0);  es0 += e0;
    }
    const float inv = 1.0f / (es0 + es1);
    float* op = out + (size_t)n * HC + c2;
    op[0] = (ax0 + ax1) * inv + bias[c2];
    op[1] = (ay0 + ay1) * inv + bias[c2 + 1];
}

// ---------------------------------------------------------------------------
extern "C" void kernel_launch(void* const* d_in, const int* in_sizes, int n_in,
                              void* d_out, int out_size, void* d_ws, size_t ws_size,
                              hipStream_t stream) {
    const float* h       = (const float*)d_in[0];
    const int*   src     = (const int*)d_in[1];
    const int*   dst     = (const int*)d_in[2];
    const float* W       = (const float*)d_in[3];
    const float* att_src = (const float*)d_in[4];
    const float* att_dst = (const float*)d_in[5];
    const float* bias    = (const float*)d_in[6];
    float*       out     = (float*)d_out;

    const int N = in_sizes[0] / IN_F;   // 50000
    const int E = in_sizes[1];          // 800000
    const int TOT = E + N;
    const int Mpad = (N + 63) & ~63;

    // Workspace layout:
    // htb[N*128] bf16 | a_s[N*4] f32 | a_d[N*4] f32 | cnt[N] | row_start[N+1]
    // | blk_sums[64] | pad | esd[TOT] int2 | exf[TOT*4] f32 | Wt[128*512] bf16
    // | hbf[Mpad*512] bf16
    unsigned short* htb = (unsigned short*)d_ws;
    float* a_s = (float*)(htb + (size_t)N * HC);
    float* a_d = a_s + (size_t)N * NH;
    int*   cnt = (int*)(a_d + (size_t)N * NH);
    int*   row_start = cnt + N;
    int*   blk_sums  = row_start + (N + 1);
    size_t off = ((size_t)((char*)(blk_sums + 64) - (char*)d_ws) + 15) & ~(size_t)15;
    int2*  esd = (int2*)((char*)d_ws + off);
    float* exf = (float*)(esd + TOT);
    unsigned short* Wt  = (unsigned short*)(exf + (size_t)TOT * NH);
    unsigned short* hbf = Wt + (size_t)IN_F * HC;   // [Mpad][512] bf16

    const int nb = (N + SCAN_ELEMS - 1) / SCAN_ELEMS;

    // --- CSR build ---
    init_counts<<<(N + 255) / 256, 256, 0, stream>>>(cnt, N);
    hist_edges<<<(E + 255) / 256, 256, 0, stream>>>(dst, cnt, E);
    scan1<<<nb, 256, 0, stream>>>(cnt, row_start, blk_sums, N);
    scan2<<<1, 64, 0, stream>>>(blk_sums, nb);
    scan3<<<(N + 255) / 256, 256, 0, stream>>>(row_start, cnt, blk_sums, N, TOT);
    scatter_edges<<<(TOT + 255) / 256, 256, 0, stream>>>(src, dst, cnt, esd, E, N);

    // --- node transform (MFMA, bf16 in/out) ---
    prep_w<<<(IN_F * HC + 255) / 256, 256, 0, stream>>>(W, Wt);
    {
        const int n_elems = N * IN_F;
        const int n_pad   = Mpad * IN_F;
        cvt_h<<<(n_pad / 8 + 255) / 256, 256, 0, stream>>>(h, (unsigned*)hbf,
                                                           n_elems, n_pad);
    }
    gemm_bf16<<<Mpad / 64, 256, 0, stream>>>(hbf, Wt, htb, N);
    node_logits<<<(N * NH + 255) / 256, 256, 0, stream>>>((const unsigned*)htb,
                                                          att_src, att_dst,
                                                          a_s, a_d, N);

    // --- edge exponentials (once per edge-head) ---
    edge_exf<<<(TOT + 255) / 256, 256, 0, stream>>>(esd, a_s, a_d,
                                                    (float4*)exf, TOT);

    // --- fused softmax + aggregation ---
    aggregate_csr<<<(N + 3) / 4, 256, 0, stream>>>(row_start, esd, exf,
                                                   (const unsigned*)htb, bias,
                                                   out, N);
}

// Round 10
// 220.816 us; speedup vs baseline: 1.0394x; 1.0394x over previous
//
#include <hip/hip_runtime.h>
#include <math.h>

// Problem constants (fixed by reference): IN=512, H=4, C=32, H*C=128.
constexpr int IN_F = 512;
constexpr int NH   = 4;
constexpr int CH   = 32;
constexpr int HC   = 128;   // NH*CH
constexpr int SCAN_ELEMS = 1024;

typedef short  short8 __attribute__((ext_vector_type(8)));
typedef float  f32x4  __attribute__((ext_vector_type(4)));

typedef __attribute__((address_space(3))) void as3_void;
typedef __attribute__((address_space(1))) void as1_void;
#define GLOAD_LDS16(g, l) \
    __builtin_amdgcn_global_load_lds((const as1_void*)(g), (as3_void*)(l), 16, 0, 0)

__device__ __forceinline__ unsigned short f2bf(float f) {
    unsigned u = __float_as_uint(f);
    unsigned r = (u + 0x7fff + ((u >> 16) & 1)) >> 16;   // RNE
    return (unsigned short)r;
}
__device__ __forceinline__ float bf2f(unsigned short b) {
    return __uint_as_float(((unsigned)b) << 16);
}
// unpack packed bf16x2 (u32) -> two floats
__device__ __forceinline__ float bfu_lo(unsigned u) {
    return __uint_as_float(u << 16);
}
__device__ __forceinline__ float bfu_hi(unsigned u) {
    return __uint_as_float(u & 0xffff0000u);
}
__device__ __forceinline__ float sig_exp(float x) {
    return __expf(1.0f / (1.0f + __expf(-x)));
}

// ---------------------------------------------------------------------------
// W[512x128] fp32 -> Wt[128x512] bf16 (transposed).
// ---------------------------------------------------------------------------
__global__ void prep_w(const float* __restrict__ W,
                       unsigned short* __restrict__ Wt) {
    int t = blockIdx.x * blockDim.x + threadIdx.x;
    if (t >= IN_F * HC) return;
    int k = t >> 7, n = t & 127;
    Wt[(size_t)n * IN_F + k] = f2bf(W[t]);
}

// ---------------------------------------------------------------------------
// h fp32 [M*512] -> bf16 [Mpad*512], zero-padded rows.
// ---------------------------------------------------------------------------
__global__ void cvt_h(const float* __restrict__ h, unsigned* __restrict__ hb,
                      int n_elems, int n_pad) {
    int i8 = (blockIdx.x * blockDim.x + threadIdx.x) * 8;
    if (i8 >= n_pad) return;
    uint4 o;
    if (i8 < n_elems) {
        float4 v0 = *(const float4*)(h + i8);
        float4 v1 = *(const float4*)(h + i8 + 4);
        o.x = (unsigned)f2bf(v0.x) | ((unsigned)f2bf(v0.y) << 16);
        o.y = (unsigned)f2bf(v0.z) | ((unsigned)f2bf(v0.w) << 16);
        o.z = (unsigned)f2bf(v1.x) | ((unsigned)f2bf(v1.y) << 16);
        o.w = (unsigned)f2bf(v1.z) | ((unsigned)f2bf(v1.w) << 16);
    } else {
        o = make_uint4(0, 0, 0, 0);
    }
    *(uint4*)(hb + i8 / 2) = o;
}

// ---------------------------------------------------------------------------
// LDS fragment reader: rows of 128 B (64 bf16), XOR-swizzled 16B chunks:
// byte = row*128 + (b ^ ((row&7)<<4)).
// ---------------------------------------------------------------------------
__device__ __forceinline__ short8 frag_read(const char* tile, int row, int kb) {
    const int sw = (row & 7) << 4;
    const int b0 = row * 128 + ((kb)      ^ sw);
    const int b1 = row * 128 + ((kb + 32) ^ sw);
    ushort4 lo = *(const ushort4*)(tile + b0);
    ushort4 hi = *(const ushort4*)(tile + b1);
    short8 f;
    f[0] = (short)lo.x; f[1] = (short)lo.y; f[2] = (short)lo.z; f[3] = (short)lo.w;
    f[4] = (short)hi.x; f[5] = (short)hi.y; f[6] = (short)hi.z; f[7] = (short)hi.w;
    return f;
}

// ---------------------------------------------------------------------------
// GEMM: htb[M x 128] (bf16) = hbf[Mpad x 512] @ Wt^T, m97-style staging.
// BM=64, BN=128, BK=64. 256 threads = 4 waves (2x2), wave tile 32x64.
// ---------------------------------------------------------------------------
__global__ __launch_bounds__(256) void gemm_bf16(
        const unsigned short* __restrict__ Abf,   // [Mpad][512]
        const unsigned short* __restrict__ Wt,    // [128][512]
        unsigned short* __restrict__ C16, int M) {
    __shared__ __align__(16) char smem[24576];
    char* As = smem;          // 8 KB
    char* Bs = smem + 8192;   // 16 KB

    const int tid  = threadIdx.x;
    const int lane = tid & 63;
    const int wave = tid >> 6;
    const int wr  = wave & 1;       // row half (32 rows)
    const int wcq = wave >> 1;      // col half (64 cols)
    const int brow = blockIdx.x * 64;
    const int lr = lane & 15;
    const int lg = lane >> 4;

    f32x4 acc[2][4];
#pragma unroll
    for (int i = 0; i < 2; ++i)
#pragma unroll
        for (int j = 0; j < 4; ++j)
            acc[i][j] = f32x4{0.f, 0.f, 0.f, 0.f};

    for (int kc = 0; kc < IN_F; kc += 64) {
        __syncthreads();   // prior compute done before overwrite
        // ---- stage A (2 chunks/thread), pre-swizzled global source ----
#pragma unroll
        for (int p = 0; p < 2; ++p) {
            const int c = tid + 256 * p;
            const int r = c >> 3, j = c & 7;
            const unsigned short* src = Abf + (size_t)(brow + r) * IN_F + kc
                                        + ((j ^ (r & 7)) << 3);
            GLOAD_LDS16(src, As + wave * 1024 + p * 4096);
        }
        // ---- stage B (4 chunks/thread) ----
#pragma unroll
        for (int p = 0; p < 4; ++p) {
            const int c = tid + 256 * p;
            const int n = c >> 3, j = c & 7;
            const unsigned short* src = Wt + (size_t)n * IN_F + kc
                                        + ((j ^ (n & 7)) << 3);
            GLOAD_LDS16(src, Bs + wave * 1024 + p * 4096);
        }
        __syncthreads();   // drains vmcnt before ds_read

        // ---- compute: 2 k-steps of 32 ----
#pragma unroll
        for (int ks = 0; ks < 2; ++ks) {
            const int kb = ks * 64 + 8 * lg;
            short8 af[2];
#pragma unroll
            for (int mi = 0; mi < 2; ++mi)
                af[mi] = frag_read(As, wr * 32 + mi * 16 + lr, kb);
            short8 bf[4];
#pragma unroll
            for (int ni = 0; ni < 4; ++ni)
                bf[ni] = frag_read(Bs, wcq * 64 + ni * 16 + lr, kb);
#pragma unroll
            for (int mi = 0; mi < 2; ++mi)
#pragma unroll
                for (int ni = 0; ni < 4; ++ni)
                    acc[mi][ni] = __builtin_amdgcn_mfma_f32_16x16x32_bf16(
                        af[mi], bf[ni], acc[mi][ni], 0, 0, 0);
        }
    }

    // ---- epilogue: bf16 store; C/D layout col=lane&15, row=4*(lane>>4)+reg
#pragma unroll
    for (int mi = 0; mi < 2; ++mi) {
        const int r0 = brow + wr * 32 + mi * 16 + 4 * lg;
#pragma unroll
        for (int ni = 0; ni < 4; ++ni) {
            const int c0 = wcq * 64 + ni * 16 + lr;
#pragma unroll
            for (int j = 0; j < 4; ++j) {
                const int r = r0 + j;
                if (r < M) C16[(size_t)r * HC + c0] = f2bf(acc[mi][ni][j]);
            }
        }
    }
}

// ---------------------------------------------------------------------------
// Per-(node,head) attention logits from bf16 ht.
// ---------------------------------------------------------------------------
__global__ void node_logits(const unsigned* __restrict__ htb32,
                            const float* __restrict__ att_src,
                            const float* __restrict__ att_dst,
                            float* __restrict__ a_s, float* __restrict__ a_d,
                            int N) {
    int t = blockIdx.x * blockDim.x + threadIdx.x;
    if (t >= N * NH) return;
    const int n  = t >> 2;
    const int hh = t & 3;
    const unsigned* p = htb32 + (size_t)n * (HC / 2) + hh * (CH / 2);
    const float* ps = att_src + hh * CH;
    const float* pd = att_dst + hh * CH;
    float s = 0.f, d = 0.f;
#pragma unroll
    for (int i = 0; i < CH / 2; i += 2) {
        uint2 u = *(const uint2*)(p + i);
        float4 as = *(const float4*)(ps + 2 * i);
        float4 ad = *(const float4*)(pd + 2 * i);
        float v0 = bfu_lo(u.x), v1 = bfu_hi(u.x);
        float v2 = bfu_lo(u.y), v3 = bfu_hi(u.y);
        s += v0 * as.x + v1 * as.y + v2 * as.z + v3 * as.w;
        d += v0 * ad.x + v1 * ad.y + v2 * ad.z + v3 * ad.w;
    }
    a_s[t] = s;
    a_d[t] = d;
}

// ---------------------------------------------------------------------------
// CSR build.
// ---------------------------------------------------------------------------
__global__ void init_counts(int* __restrict__ counts, int N) {
    int i = blockIdx.x * blockDim.x + threadIdx.x;
    if (i < N) counts[i] = 1;   // self loop
}

__global__ void hist_edges(const int* __restrict__ dst, int* __restrict__ counts, int E) {
    int e = blockIdx.x * blockDim.x + threadIdx.x;
    if (e < E) atomicAdd(&counts[dst[e]], 1);
}

__global__ __launch_bounds__(256) void scan1(const int* __restrict__ counts,
                                             int* __restrict__ row_start,
                                             int* __restrict__ blk_sums, int N) {
    __shared__ int sh[256];
    const int b = blockIdx.x, t = threadIdx.x;
    const int base = b * SCAN_ELEMS + t * 4;
    int v[4], s = 0;
#pragma unroll
    for (int i = 0; i < 4; ++i) {
        v[i] = (base + i < N) ? counts[base + i] : 0;
        s += v[i];
    }
    sh[t] = s;
    __syncthreads();
    for (int off = 1; off < 256; off <<= 1) {
        int x = (t >= off) ? sh[t - off] : 0;
        __syncthreads();
        sh[t] += x;
        __syncthreads();
    }
    int run = sh[t] - s;
#pragma unroll
    for (int i = 0; i < 4; ++i) {
        if (base + i < N) row_start[base + i] = run;
        run += v[i];
    }
    if (t == 255) blk_sums[b] = sh[255];
}

__global__ void scan2(int* __restrict__ blk_sums, int nb) {
    if (threadIdx.x == 0 && blockIdx.x == 0) {
        int acc = 0;
        for (int i = 0; i < nb; ++i) { int v = blk_sums[i]; blk_sums[i] = acc; acc += v; }
    }
}

__global__ void scan3(int* __restrict__ row_start, int* __restrict__ cursor,
                      const int* __restrict__ blk_sums, int N, int total) {
    int i = blockIdx.x * blockDim.x + threadIdx.x;
    if (i < N) {
        int v = row_start[i] + blk_sums[i / SCAN_ELEMS];
        row_start[i] = v;
        cursor[i] = v;
    }
    if (i == 0) row_start[N] = total;
}

// Scatter src ids (u16, N<65536) into CSR slot order — 2B scattered stores.
__global__ void scatter_edges(const int* __restrict__ src, const int* __restrict__ dst,
                              int* __restrict__ cursor,
                              unsigned short* __restrict__ esrc,
                              int E, int N) {
    int e = blockIdx.x * blockDim.x + threadIdx.x;
    if (e >= E + N) return;
    const int s = (e < E) ? src[e] : (e - E);
    const int d = (e < E) ? dst[e] : (e - E);
    int pos = atomicAdd(&cursor[d], 1);
    esrc[pos] = (unsigned short)s;
}

// ---------------------------------------------------------------------------
// Node-centric edge exponentials in CSR order (dst is implicit):
// thread t=(n,h): for j in [rs,re): exf[j*4+h] = sig_exp(a_s[esrc[j],h]+a_d[n,h])
// Writes are CSR-sequential (4 heads x 4B = 16B contiguous per edge slot).
// ---------------------------------------------------------------------------
__global__ void edge_exf_csr(const int* __restrict__ row_start,
                             const unsigned short* __restrict__ esrc,
                             const float* __restrict__ a_s,
                             const float* __restrict__ a_d,
                             float* __restrict__ exf, int N) {
    int t = blockIdx.x * blockDim.x + threadIdx.x;
    if (t >= N * NH) return;
    const int n  = t >> 2;
    const int hh = t & 3;
    const float ad = a_d[t & ~3 | hh];   // a_d[n*4+hh] == a_d[t]
    const int rs = row_start[n], re = row_start[n + 1];
    for (int j = rs; j < re; ++j) {
        const int s = esrc[j];
        exf[(size_t)j * NH + hh] = sig_exp(a_s[s * NH + hh] + ad);
    }
}

// ---------------------------------------------------------------------------
// Fused softmax + aggregation, one wave per dst node, bf16 ht gather,
// precomputed edge exponentials (pure FMA loop).
// Lane l: u32 = 2 channels (c2 = 2l, 2l+1), head = l>>4.
// ---------------------------------------------------------------------------
__global__ __launch_bounds__(256) void aggregate_csr(
        const int* __restrict__ row_start,
        const unsigned short* __restrict__ esrc,
        const float* __restrict__ exf,
        const unsigned* __restrict__ htb32, const float* __restrict__ bias,
        float* __restrict__ out, int N) {
    const int n = blockIdx.x * 4 + (threadIdx.x >> 6);
    if (n >= N) return;
    const int lane = threadIdx.x & 63;
    const int hh   = lane >> 4;
    const int c2   = lane * 2;

    const int rs = row_start[n], re = row_start[n + 1];

    float ax0 = 0.f, ay0 = 0.f, es0 = 0.f;
    float ax1 = 0.f, ay1 = 0.f, es1 = 0.f;
    int j = rs;
    for (; j + 1 < re; j += 2) {
        const int s0 = esrc[j], s1 = esrc[j + 1];
        const float e0 = exf[(size_t)j * NH + hh];
        const float e1 = exf[(size_t)(j + 1) * NH + hh];
        const unsigned u0 = htb32[(size_t)s0 * (HC / 2) + lane];
        const unsigned u1 = htb32[(size_t)s1 * (HC / 2) + lane];
        ax0 += e0 * bfu_lo(u0);  ay0 += e0 * bfu_hi(u0);  es0 += e0;
        ax1 += e1 * bfu_lo(u1);  ay1 += e1 * bfu_hi(u1);  es1 += e1;
    }
    if (j < re) {
        const int s0 = esrc[j];
        const float e0 = exf[(size_t)j * NH + hh];
        const unsigned u0 = htb32[(size_t)s0 * (HC / 2) + lane];
        ax0 += e0 * bfu_lo(u0);  ay0 += e0 * bfu_hi(u0);  es0 += e0;
    }
    const float inv = 1.0f / (es0 + es1);
    float* op = out + (size_t)n * HC + c2;
    op[0] = (ax0 + ax1) * inv + bias[c2];
    op[1] = (ay0 + ay1) * inv + bias[c2 + 1];
}

// ---------------------------------------------------------------------------
extern "C" void kernel_launch(void* const* d_in, const int* in_sizes, int n_in,
                              void* d_out, int out_size, void* d_ws, size_t ws_size,
                              hipStream_t stream) {
    const float* h       = (const float*)d_in[0];
    const int*   src     = (const int*)d_in[1];
    const int*   dst     = (const int*)d_in[2];
    const float* W       = (const float*)d_in[3];
    const float* att_src = (const float*)d_in[4];
    const float* att_dst = (const float*)d_in[5];
    const float* bias    = (const float*)d_in[6];
    float*       out     = (float*)d_out;

    const int N = in_sizes[0] / IN_F;   // 50000
    const int E = in_sizes[1];          // 800000
    const int TOT = E + N;
    const int Mpad = (N + 63) & ~63;

    // Workspace layout:
    // htb[N*128] bf16 | a_s[N*4] f32 | a_d[N*4] f32 | cnt[N] | row_start[N+1]
    // | blk_sums[64] | pad | esrc[TOT] u16 | pad | exf[TOT*4] f32
    // | Wt[128*512] bf16 | hbf[Mpad*512] bf16
    unsigned short* htb = (unsigned short*)d_ws;
    float* a_s = (float*)(htb + (size_t)N * HC);
    float* a_d = a_s + (size_t)N * NH;
    int*   cnt = (int*)(a_d + (size_t)N * NH);
    int*   row_start = cnt + N;
    int*   blk_sums  = row_start + (N + 1);
    size_t off = ((size_t)((char*)(blk_sums + 64) - (char*)d_ws) + 15) & ~(size_t)15;
    unsigned short* esrc = (unsigned short*)((char*)d_ws + off);
    size_t off2 = ((size_t)((char*)(esrc + TOT) - (char*)d_ws) + 15) & ~(size_t)15;
    float* exf = (float*)((char*)d_ws + off2);
    unsigned short* Wt  = (unsigned short*)(exf + (size_t)TOT * NH);
    unsigned short* hbf = Wt + (size_t)IN_F * HC;   // [Mpad][512] bf16

    const int nb = (N + SCAN_ELEMS - 1) / SCAN_ELEMS;

    // --- CSR build ---
    init_counts<<<(N + 255) / 256, 256, 0, stream>>>(cnt, N);
    hist_edges<<<(E + 255) / 256, 256, 0, stream>>>(dst, cnt, E);
    scan1<<<nb, 256, 0, stream>>>(cnt, row_start, blk_sums, N);
    scan2<<<1, 64, 0, stream>>>(blk_sums, nb);
    scan3<<<(N + 255) / 256, 256, 0, stream>>>(row_start, cnt, blk_sums, N, TOT);
    scatter_edges<<<(TOT + 255) / 256, 256, 0, stream>>>(src, dst, cnt, esrc, E, N);

    // --- node transform (MFMA, bf16 in/out) ---
    prep_w<<<(IN_F * HC + 255) / 256, 256, 0, stream>>>(W, Wt);
    {
        const int n_elems = N * IN_F;
        const int n_pad   = Mpad * IN_F;
        cvt_h<<<(n_pad / 8 + 255) / 256, 256, 0, stream>>>(h, (unsigned*)hbf,
                                                           n_elems, n_pad);
    }
    gemm_bf16<<<Mpad / 64, 256, 0, stream>>>(hbf, Wt, htb, N);
    node_logits<<<(N * NH + 255) / 256, 256, 0, stream>>>((const unsigned*)htb,
                                                          att_src, att_dst,
                                                          a_s, a_d, N);

    // --- edge exponentials in CSR order (dst implicit) ---
    edge_exf_csr<<<(N * NH + 255) / 256, 256, 0, stream>>>(row_start, esrc,
                                                           a_s, a_d, exf, N);

    // --- fused softmax + aggregation ---
    aggregate_csr<<<(N + 3) / 4, 256, 0, stream>>>(row_start, esrc, exf,
                                                   (const unsigned*)htb, bias,
                                                   out, N);
}

// Round 11
// 206.237 us; speedup vs baseline: 1.1129x; 1.0707x over previous
//
#include <hip/hip_runtime.h>
#include <hip/hip_bf16.h>
#include <math.h>

// Problem constants (fixed by reference): IN=512, H=4, C=32, H*C=128.
constexpr int IN_F = 512;
constexpr int NH   = 4;
constexpr int CH   = 32;
constexpr int HC   = 128;   // NH*CH
constexpr int SCAN_ELEMS = 1024;

typedef short  short8 __attribute__((ext_vector_type(8)));
typedef float  f32x4  __attribute__((ext_vector_type(4)));

typedef __attribute__((address_space(3))) void as3_void;
typedef __attribute__((address_space(1))) void as1_void;
#define GLOAD_LDS16(g, l) \
    __builtin_amdgcn_global_load_lds((const as1_void*)(g), (as3_void*)(l), 16, 0, 0)

__device__ __forceinline__ unsigned short f2bf(float f) {
    unsigned u = __float_as_uint(f);
    unsigned r = (u + 0x7fff + ((u >> 16) & 1)) >> 16;   // RNE
    return (unsigned short)r;
}
// unpack packed bf16x2 (u32) -> two floats
__device__ __forceinline__ float bfu_lo(unsigned u) {
    return __uint_as_float(u << 16);
}
__device__ __forceinline__ float bfu_hi(unsigned u) {
    return __uint_as_float(u & 0xffff0000u);
}
__device__ __forceinline__ float sig_exp(float x) {
    return __expf(1.0f / (1.0f + __expf(-x)));
}

// ---------------------------------------------------------------------------
// W[512x128] fp32 -> Wt[128x512] bf16 (transposed).
// ---------------------------------------------------------------------------
__global__ void prep_w(const float* __restrict__ W,
                       unsigned short* __restrict__ Wt) {
    int t = blockIdx.x * blockDim.x + threadIdx.x;
    if (t >= IN_F * HC) return;
    int k = t >> 7, n = t & 127;
    Wt[(size_t)n * IN_F + k] = f2bf(W[t]);
}

// ---------------------------------------------------------------------------
// LDS fragment readers.
// B (bf16): rows of 128 B (64 bf16), XOR-swizzled 16B chunks:
//   byte = row*128 + (b ^ ((row&7)<<4)).
// ---------------------------------------------------------------------------
__device__ __forceinline__ short8 frag_read(const char* tile, int row, int kb) {
    const int sw = (row & 7) << 4;
    const int b0 = row * 128 + ((kb)      ^ sw);
    const int b1 = row * 128 + ((kb + 32) ^ sw);
    ushort4 lo = *(const ushort4*)(tile + b0);
    ushort4 hi = *(const ushort4*)(tile + b1);
    short8 f;
    f[0] = (short)lo.x; f[1] = (short)lo.y; f[2] = (short)lo.z; f[3] = (short)lo.w;
    f[4] = (short)hi.x; f[5] = (short)hi.y; f[6] = (short)hi.z; f[7] = (short)hi.w;
    return f;
}

// A (f32): rows of 256 B (64 f32), XOR-swizzled 16B chunks (chunk j of row r
// stored at chunk j ^ (r&7)); convert to bf16 at read time (v_cvt_pk_bf16_f32).
// jb = f32-chunk index of the fragment's low half (= ks*8 + lg).
__device__ __forceinline__ short8 frag_read_a(const char* tile, int row, int jb) {
    const int sw = row & 7;
    const float4 lo = *(const float4*)(tile + row * 256 + (((jb)     ^ sw) << 4));
    const float4 hi = *(const float4*)(tile + row * 256 + (((jb + 4) ^ sw) << 4));
    __hip_bfloat162 p0 = __float22bfloat162_rn(float2{lo.x, lo.y});
    __hip_bfloat162 p1 = __float22bfloat162_rn(float2{lo.z, lo.w});
    __hip_bfloat162 p2 = __float22bfloat162_rn(float2{hi.x, hi.y});
    __hip_bfloat162 p3 = __float22bfloat162_rn(float2{hi.z, hi.w});
    unsigned u0 = *(unsigned*)&p0, u1 = *(unsigned*)&p1;
    unsigned u2 = *(unsigned*)&p2, u3 = *(unsigned*)&p3;
    short8 f;
    f[0] = (short)u0; f[1] = (short)(u0 >> 16);
    f[2] = (short)u1; f[3] = (short)(u1 >> 16);
    f[4] = (short)u2; f[5] = (short)(u2 >> 16);
    f[6] = (short)u3; f[7] = (short)(u3 >> 16);
    return f;
}

// ---------------------------------------------------------------------------
// GEMM: htb[M x 128] (bf16) = h[M x 512] (f32, staged direct) @ Wt^T.
// BM=64, BN=128, BK=64. 256 threads = 4 waves (2x2), wave tile 32x64.
// LDS 32 KB: A f32 [64][64] (16K) + B bf16 [128][64] (16K); linear dest via
// global_load_lds, swizzle via pre-swizzled GLOBAL source.
// ---------------------------------------------------------------------------
__global__ __launch_bounds__(256) void gemm_f32a(
        const float* __restrict__ A,              // [M][512] f32
        const unsigned short* __restrict__ Wt,    // [128][512] bf16
        unsigned short* __restrict__ C16, int M) {
    __shared__ __align__(16) char smem[32768];
    char* As = smem;           // 16 KB (f32 tile)
    char* Bs = smem + 16384;   // 16 KB (bf16 tile)

    const int tid  = threadIdx.x;
    const int lane = tid & 63;
    const int wave = tid >> 6;
    const int wr  = wave & 1;       // row half (32 rows)
    const int wcq = wave >> 1;      // col half (64 cols)
    const int brow = blockIdx.x * 64;
    const int lr = lane & 15;
    const int lg = lane >> 4;

    f32x4 acc[2][4];
#pragma unroll
    for (int i = 0; i < 2; ++i)
#pragma unroll
        for (int j = 0; j < 4; ++j)
            acc[i][j] = f32x4{0.f, 0.f, 0.f, 0.f};

    for (int kc = 0; kc < IN_F; kc += 64) {
        __syncthreads();   // prior compute done before overwrite
        // ---- stage A f32 (4 chunks/thread); rows >= M redirected to row 0 ----
#pragma unroll
        for (int p = 0; p < 4; ++p) {
            const int c = tid + 256 * p;
            const int r = c >> 4, j = c & 15;
            int gr = brow + r;
            if (gr >= M) gr = 0;   // harmless garbage; C rows >= M never stored
            const float* srcp = A + (size_t)gr * IN_F + kc + ((j ^ (r & 7)) << 2);
            GLOAD_LDS16(srcp, As + wave * 1024 + p * 4096);
        }
        // ---- stage B bf16 (4 chunks/thread) ----
#pragma unroll
        for (int p = 0; p < 4; ++p) {
            const int c = tid + 256 * p;
            const int n = c >> 3, j = c & 7;
            const unsigned short* srcp = Wt + (size_t)n * IN_F + kc
                                         + ((j ^ (n & 7)) << 3);
            GLOAD_LDS16(srcp, Bs + wave * 1024 + p * 4096);
        }
        __syncthreads();   // drains vmcnt before ds_read

        // ---- compute: 2 k-steps of 32 ----
#pragma unroll
        for (int ks = 0; ks < 2; ++ks) {
            const int jb = ks * 8 + lg;        // A f32-chunk index
            const int kb = ks * 64 + 8 * lg;   // B byte offset
            short8 af[2];
#pragma unroll
            for (int mi = 0; mi < 2; ++mi)
                af[mi] = frag_read_a(As, wr * 32 + mi * 16 + lr, jb);
            short8 bf[4];
#pragma unroll
            for (int ni = 0; ni < 4; ++ni)
                bf[ni] = frag_read(Bs, wcq * 64 + ni * 16 + lr, kb);
#pragma unroll
            for (int mi = 0; mi < 2; ++mi)
#pragma unroll
                for (int ni = 0; ni < 4; ++ni)
                    acc[mi][ni] = __builtin_amdgcn_mfma_f32_16x16x32_bf16(
                        af[mi], bf[ni], acc[mi][ni], 0, 0, 0);
        }
    }

    // ---- epilogue: bf16 store; C/D layout col=lane&15, row=4*(lane>>4)+reg
#pragma unroll
    for (int mi = 0; mi < 2; ++mi) {
        const int r0 = brow + wr * 32 + mi * 16 + 4 * lg;
#pragma unroll
        for (int ni = 0; ni < 4; ++ni) {
            const int c0 = wcq * 64 + ni * 16 + lr;
#pragma unroll
            for (int j = 0; j < 4; ++j) {
                const int r = r0 + j;
                if (r < M) C16[(size_t)r * HC + c0] = f2bf(acc[mi][ni][j]);
            }
        }
    }
}

// ---------------------------------------------------------------------------
// Per-(node,head) attention logits from bf16 ht.
// ---------------------------------------------------------------------------
__global__ void node_logits(const unsigned* __restrict__ htb32,
                            const float* __restrict__ att_src,
                            const float* __restrict__ att_dst,
                            float* __restrict__ a_s, float* __restrict__ a_d,
                            int N) {
    int t = blockIdx.x * blockDim.x + threadIdx.x;
    if (t >= N * NH) return;
    const int n  = t >> 2;
    const int hh = t & 3;
    const unsigned* p = htb32 + (size_t)n * (HC / 2) + hh * (CH / 2);
    const float* ps = att_src + hh * CH;
    const float* pd = att_dst + hh * CH;
    float s = 0.f, d = 0.f;
#pragma unroll
    for (int i = 0; i < CH / 2; i += 2) {
        uint2 u = *(const uint2*)(p + i);
        float4 as = *(const float4*)(ps + 2 * i);
        float4 ad = *(const float4*)(pd + 2 * i);
        float v0 = bfu_lo(u.x), v1 = bfu_hi(u.x);
        float v2 = bfu_lo(u.y), v3 = bfu_hi(u.y);
        s += v0 * as.x + v1 * as.y + v2 * as.z + v3 * as.w;
        d += v0 * ad.x + v1 * ad.y + v2 * ad.z + v3 * ad.w;
    }
    a_s[t] = s;
    a_d[t] = d;
}

// ---------------------------------------------------------------------------
// CSR build.
// ---------------------------------------------------------------------------
__global__ void init_counts(int* __restrict__ counts, int N) {
    int i = blockIdx.x * blockDim.x + threadIdx.x;
    if (i < N) counts[i] = 1;   // self loop
}

__global__ void hist_edges(const int* __restrict__ dst, int* __restrict__ counts, int E) {
    int e = blockIdx.x * blockDim.x + threadIdx.x;
    if (e < E) atomicAdd(&counts[dst[e]], 1);
}

__global__ __launch_bounds__(256) void scan1(const int* __restrict__ counts,
                                             int* __restrict__ row_start,
                                             int* __restrict__ blk_sums, int N) {
    __shared__ int sh[256];
    const int b = blockIdx.x, t = threadIdx.x;
    const int base = b * SCAN_ELEMS + t * 4;
    int v[4], s = 0;
#pragma unroll
    for (int i = 0; i < 4; ++i) {
        v[i] = (base + i < N) ? counts[base + i] : 0;
        s += v[i];
    }
    sh[t] = s;
    __syncthreads();
    for (int off = 1; off < 256; off <<= 1) {
        int x = (t >= off) ? sh[t - off] : 0;
        __syncthreads();
        sh[t] += x;
        __syncthreads();
    }
    int run = sh[t] - s;
#pragma unroll
    for (int i = 0; i < 4; ++i) {
        if (base + i < N) row_start[base + i] = run;
        run += v[i];
    }
    if (t == 255) blk_sums[b] = sh[255];
}

__global__ void scan2(int* __restrict__ blk_sums, int nb) {
    if (threadIdx.x == 0 && blockIdx.x == 0) {
        int acc = 0;
        for (int i = 0; i < nb; ++i) { int v = blk_sums[i]; blk_sums[i] = acc; acc += v; }
    }
}

__global__ void scan3(int* __restrict__ row_start, int* __restrict__ cursor,
                      const int* __restrict__ blk_sums, int N, int total) {
    int i = blockIdx.x * blockDim.x + threadIdx.x;
    if (i < N) {
        int v = row_start[i] + blk_sums[i / SCAN_ELEMS];
        row_start[i] = v;
        cursor[i] = v;
    }
    if (i == 0) row_start[N] = total;
}

// Scatter src ids (u16, N<65536) into CSR slot order — 2B scattered stores.
__global__ void scatter_edges(const int* __restrict__ src, const int* __restrict__ dst,
                              int* __restrict__ cursor,
                              unsigned short* __restrict__ esrc,
                              int E, int N) {
    int e = blockIdx.x * blockDim.x + threadIdx.x;
    if (e >= E + N) return;
    const int s = (e < E) ? src[e] : (e - E);
    const int d = (e < E) ? dst[e] : (e - E);
    int pos = atomicAdd(&cursor[d], 1);
    esrc[pos] = (unsigned short)s;
}

// ---------------------------------------------------------------------------
// Node-centric edge exponentials + denominators, one thread per node:
// for j in [rs,re): exf[j] = sig_exp(a_s[esrc[j]] + a_d[n]) (float4 over heads)
// denom[n] = sum_j exf[j].  Writes CSR-sequential (16B per edge slot).
// ---------------------------------------------------------------------------
__global__ void edge_exf_csr(const int* __restrict__ row_start,
                             const unsigned short* __restrict__ esrc,
                             const float4* __restrict__ a_s4,
                             const float4* __restrict__ a_d4,
                             float4* __restrict__ exf4,
                             float4* __restrict__ denom4, int N) {
    int n = blockIdx.x * blockDim.x + threadIdx.x;
    if (n >= N) return;
    const float4 ad = a_d4[n];
    const int rs = row_start[n], re = row_start[n + 1];
    float sx = 0.f, sy = 0.f, sz = 0.f, sw = 0.f;
    for (int j = rs; j < re; ++j) {
        const int s = esrc[j];
        const float4 as = a_s4[s];
        float4 r;
        r.x = sig_exp(as.x + ad.x);
        r.y = sig_exp(as.y + ad.y);
        r.z = sig_exp(as.z + ad.z);
        r.w = sig_exp(as.w + ad.w);
        exf4[j] = r;
        sx += r.x; sy += r.y; sz += r.z; sw += r.w;
    }
    denom4[n] = make_float4(sx, sy, sz, sw);
}

// ---------------------------------------------------------------------------
// Weighted aggregation, one wave per dst node, bf16 ht gather, precomputed
// edge exponentials AND denominators (pure FMA loop, no es accumulation).
// Lane l: u32 = 2 channels (c2 = 2l, 2l+1), head = l>>4.
// ---------------------------------------------------------------------------
__global__ __launch_bounds__(256) void aggregate_csr(
        const int* __restrict__ row_start,
        const unsigned short* __restrict__ esrc,
        const float* __restrict__ exf,
        const float* __restrict__ denom,
        const unsigned* __restrict__ htb32, const float* __restrict__ bias,
        float* __restrict__ out, int N) {
    const int n = blockIdx.x * 4 + (threadIdx.x >> 6);
    if (n >= N) return;
    const int lane = threadIdx.x & 63;
    const int hh   = lane >> 4;
    const int c2   = lane * 2;

    const int rs = row_start[n], re = row_start[n + 1];
    const float inv = 1.0f / denom[n * NH + hh];

    float ax0 = 0.f, ay0 = 0.f;
    float ax1 = 0.f, ay1 = 0.f;
    int j = rs;
    for (; j + 1 < re; j += 2) {
        const int s0 = esrc[j], s1 = esrc[j + 1];
        const float e0 = exf[(size_t)j * NH + hh];
        const float e1 = exf[(size_t)(j + 1) * NH + hh];
        const unsigned u0 = htb32[(size_t)s0 * (HC / 2) + lane];
        const unsigned u1 = htb32[(size_t)s1 * (HC / 2) + lane];
        ax0 += e0 * bfu_lo(u0);  ay0 += e0 * bfu_hi(u0);
        ax1 += e1 * bfu_lo(u1);  ay1 += e1 * bfu_hi(u1);
    }
    if (j < re) {
        const int s0 = esrc[j];
        const float e0 = exf[(size_t)j * NH + hh];
        const unsigned u0 = htb32[(size_t)s0 * (HC / 2) + lane];
        ax0 += e0 * bfu_lo(u0);  ay0 += e0 * bfu_hi(u0);
    }
    float* op = out + (size_t)n * HC + c2;
    op[0] = (ax0 + ax1) * inv + bias[c2];
    op[1] = (ay0 + ay1) * inv + bias[c2 + 1];
}

// ---------------------------------------------------------------------------
extern "C" void kernel_launch(void* const* d_in, const int* in_sizes, int n_in,
                              void* d_out, int out_size, void* d_ws, size_t ws_size,
                              hipStream_t stream) {
    const float* h       = (const float*)d_in[0];
    const int*   src     = (const int*)d_in[1];
    const int*   dst     = (const int*)d_in[2];
    const float* W       = (const float*)d_in[3];
    const float* att_src = (const float*)d_in[4];
    const float* att_dst = (const float*)d_in[5];
    const float* bias    = (const float*)d_in[6];
    float*       out     = (float*)d_out;

    const int N = in_sizes[0] / IN_F;   // 50000
    const int E = in_sizes[1];          // 800000
    const int TOT = E + N;
    const int Mpad = (N + 63) & ~63;

    // Workspace layout:
    // htb[N*128] bf16 | a_s[N*4] f32 | a_d[N*4] f32 | denom[N*4] f32 | cnt[N]
    // | row_start[N+1] | blk_sums[64] | pad | esrc[TOT] u16 | pad
    // | exf[TOT*4] f32 | Wt[128*512] bf16
    unsigned short* htb = (unsigned short*)d_ws;
    float* a_s   = (float*)(htb + (size_t)N * HC);
    float* a_d   = a_s + (size_t)N * NH;
    float* denom = a_d + (size_t)N * NH;
    int*   cnt   = (int*)(denom + (size_t)N * NH);
    int*   row_start = cnt + N;
    int*   blk_sums  = row_start + (N + 1);
    size_t off = ((size_t)((char*)(blk_sums + 64) - (char*)d_ws) + 15) & ~(size_t)15;
    unsigned short* esrc = (unsigned short*)((char*)d_ws + off);
    size_t off2 = ((size_t)((char*)(esrc + TOT) - (char*)d_ws) + 15) & ~(size_t)15;
    float* exf = (float*)((char*)d_ws + off2);
    unsigned short* Wt = (unsigned short*)(exf + (size_t)TOT * NH);

    const int nb = (N + SCAN_ELEMS - 1) / SCAN_ELEMS;

    // --- CSR build ---
    init_counts<<<(N + 255) / 256, 256, 0, stream>>>(cnt, N);
    hist_edges<<<(E + 255) / 256, 256, 0, stream>>>(dst, cnt, E);
    scan1<<<nb, 256, 0, stream>>>(cnt, row_start, blk_sums, N);
    scan2<<<1, 64, 0, stream>>>(blk_sums, nb);
    scan3<<<(N + 255) / 256, 256, 0, stream>>>(row_start, cnt, blk_sums, N, TOT);
    scatter_edges<<<(TOT + 255) / 256, 256, 0, stream>>>(src, dst, cnt, esrc, E, N);

    // --- node transform (MFMA, f32 A staged direct, bf16 out) ---
    prep_w<<<(IN_F * HC + 255) / 256, 256, 0, stream>>>(W, Wt);
    gemm_f32a<<<Mpad / 64, 256, 0, stream>>>(h, Wt, htb, N);
    node_logits<<<(N * NH + 255) / 256, 256, 0, stream>>>((const unsigned*)htb,
                                                          att_src, att_dst,
                                                          a_s, a_d, N);

    // --- edge exponentials + denominators in CSR order ---
    edge_exf_csr<<<(N + 255) / 256, 256, 0, stream>>>(row_start, esrc,
                                                      (const float4*)a_s,
                                                      (const float4*)a_d,
                                                      (float4*)exf,
                                                      (float4*)denom, N);

    // --- weighted aggregation ---
    aggregate_csr<<<(N + 3) / 4, 256, 0, stream>>>(row_start, esrc, exf, denom,
                                                   (const unsigned*)htb, bias,
                                                   out, N);
}

// Round 13
// 205.664 us; speedup vs baseline: 1.1160x; 1.0028x over previous
//
#include <hip/hip_runtime.h>
#include <hip/hip_bf16.h>
#include <math.h>

// Problem constants (fixed by reference): IN=512, H=4, C=32, H*C=128.
constexpr int IN_F = 512;
constexpr int NH   = 4;
constexpr int CH   = 32;
constexpr int HC   = 128;   // NH*CH
constexpr int SCAN_ELEMS = 1024;
constexpr int NPART = 8;           // dst partitions ~ XCDs

typedef short  short8 __attribute__((ext_vector_type(8)));
typedef float  f32x4  __attribute__((ext_vector_type(4)));

typedef __attribute__((address_space(3))) void as3_void;
typedef __attribute__((address_space(1))) void as1_void;
#define GLOAD_LDS16(g, l) \
    __builtin_amdgcn_global_load_lds((const as1_void*)(g), (as3_void*)(l), 16, 0, 0)

__device__ __forceinline__ unsigned short f2bf(float f) {
    unsigned u = __float_as_uint(f);
    unsigned r = (u + 0x7fff + ((u >> 16) & 1)) >> 16;   // RNE
    return (unsigned short)r;
}
// unpack packed bf16x2 (u32) -> two floats
__device__ __forceinline__ float bfu_lo(unsigned u) {
    return __uint_as_float(u << 16);
}
__device__ __forceinline__ float bfu_hi(unsigned u) {
    return __uint_as_float(u & 0xffff0000u);
}
__device__ __forceinline__ float sig_exp(float x) {
    return __expf(1.0f / (1.0f + __expf(-x)));
}

// ---------------------------------------------------------------------------
// W[512x128] fp32 -> Wt[128x512] bf16 (transposed).
// ---------------------------------------------------------------------------
__global__ void prep_w(const float* __restrict__ W,
                       unsigned short* __restrict__ Wt) {
    int t = blockIdx.x * blockDim.x + threadIdx.x;
    if (t >= IN_F * HC) return;
    int k = t >> 7, n = t & 127;
    Wt[(size_t)n * IN_F + k] = f2bf(W[t]);
}

// ---------------------------------------------------------------------------
// LDS fragment readers (see round-10 notes).
// ---------------------------------------------------------------------------
__device__ __forceinline__ short8 frag_read(const char* tile, int row, int kb) {
    const int sw = (row & 7) << 4;
    const int b0 = row * 128 + ((kb)      ^ sw);
    const int b1 = row * 128 + ((kb + 32) ^ sw);
    ushort4 lo = *(const ushort4*)(tile + b0);
    ushort4 hi = *(const ushort4*)(tile + b1);
    short8 f;
    f[0] = (short)lo.x; f[1] = (short)lo.y; f[2] = (short)lo.z; f[3] = (short)lo.w;
    f[4] = (short)hi.x; f[5] = (short)hi.y; f[6] = (short)hi.z; f[7] = (short)hi.w;
    return f;
}

__device__ __forceinline__ short8 frag_read_a(const char* tile, int row, int jb) {
    const int sw = row & 7;
    const float4 lo = *(const float4*)(tile + row * 256 + (((jb)     ^ sw) << 4));
    const float4 hi = *(const float4*)(tile + row * 256 + (((jb + 4) ^ sw) << 4));
    __hip_bfloat162 p0 = __float22bfloat162_rn(float2{lo.x, lo.y});
    __hip_bfloat162 p1 = __float22bfloat162_rn(float2{lo.z, lo.w});
    __hip_bfloat162 p2 = __float22bfloat162_rn(float2{hi.x, hi.y});
    __hip_bfloat162 p3 = __float22bfloat162_rn(float2{hi.z, hi.w});
    unsigned u0 = *(unsigned*)&p0, u1 = *(unsigned*)&p1;
    unsigned u2 = *(unsigned*)&p2, u3 = *(unsigned*)&p3;
    short8 f;
    f[0] = (short)u0; f[1] = (short)(u0 >> 16);
    f[2] = (short)u1; f[3] = (short)(u1 >> 16);
    f[4] = (short)u2; f[5] = (short)(u2 >> 16);
    f[6] = (short)u3; f[7] = (short)(u3 >> 16);
    return f;
}

// ---------------------------------------------------------------------------
// GEMM: htb[M x 128] (bf16) = h[M x 512] (f32, staged direct) @ Wt^T.
// ---------------------------------------------------------------------------
__global__ __launch_bounds__(256) void gemm_f32a(
        const float* __restrict__ A,              // [M][512] f32
        const unsigned short* __restrict__ Wt,    // [128][512] bf16
        unsigned short* __restrict__ C16, int M) {
    __shared__ __align__(16) char smem[32768];
    char* As = smem;           // 16 KB (f32 tile)
    char* Bs = smem + 16384;   // 16 KB (bf16 tile)

    const int tid  = threadIdx.x;
    const int lane = tid & 63;
    const int wave = tid >> 6;
    const int wr  = wave & 1;
    const int wcq = wave >> 1;
    const int brow = blockIdx.x * 64;
    const int lr = lane & 15;
    const int lg = lane >> 4;

    f32x4 acc[2][4];
#pragma unroll
    for (int i = 0; i < 2; ++i)
#pragma unroll
        for (int j = 0; j < 4; ++j)
            acc[i][j] = f32x4{0.f, 0.f, 0.f, 0.f};

    for (int kc = 0; kc < IN_F; kc += 64) {
        __syncthreads();
#pragma unroll
        for (int p = 0; p < 4; ++p) {
            const int c = tid + 256 * p;
            const int r = c >> 4, j = c & 15;
            int gr = brow + r;
            if (gr >= M) gr = 0;
            const float* srcp = A + (size_t)gr * IN_F + kc + ((j ^ (r & 7)) << 2);
            GLOAD_LDS16(srcp, As + wave * 1024 + p * 4096);
        }
#pragma unroll
        for (int p = 0; p < 4; ++p) {
            const int c = tid + 256 * p;
            const int n = c >> 3, j = c & 7;
            const unsigned short* srcp = Wt + (size_t)n * IN_F + kc
                                         + ((j ^ (n & 7)) << 3);
            GLOAD_LDS16(srcp, Bs + wave * 1024 + p * 4096);
        }
        __syncthreads();

#pragma unroll
        for (int ks = 0; ks < 2; ++ks) {
            const int jb = ks * 8 + lg;
            const int kb = ks * 64 + 8 * lg;
            short8 af[2];
#pragma unroll
            for (int mi = 0; mi < 2; ++mi)
                af[mi] = frag_read_a(As, wr * 32 + mi * 16 + lr, jb);
            short8 bf[4];
#pragma unroll
            for (int ni = 0; ni < 4; ++ni)
                bf[ni] = frag_read(Bs, wcq * 64 + ni * 16 + lr, kb);
#pragma unroll
            for (int mi = 0; mi < 2; ++mi)
#pragma unroll
                for (int ni = 0; ni < 4; ++ni)
                    acc[mi][ni] = __builtin_amdgcn_mfma_f32_16x16x32_bf16(
                        af[mi], bf[ni], acc[mi][ni], 0, 0, 0);
        }
    }

#pragma unroll
    for (int mi = 0; mi < 2; ++mi) {
        const int r0 = brow + wr * 32 + mi * 16 + 4 * lg;
#pragma unroll
        for (int ni = 0; ni < 4; ++ni) {
            const int c0 = wcq * 64 + ni * 16 + lr;
#pragma unroll
            for (int j = 0; j < 4; ++j) {
                const int r = r0 + j;
                if (r < M) C16[(size_t)r * HC + c0] = f2bf(acc[mi][ni][j]);
            }
        }
    }
}

// ---------------------------------------------------------------------------
// Per-(node,head) attention logits from bf16 ht.
// ---------------------------------------------------------------------------
__global__ void node_logits(const unsigned* __restrict__ htb32,
                            const float* __restrict__ att_src,
                            const float* __restrict__ att_dst,
                            float* __restrict__ a_s, float* __restrict__ a_d,
                            int N) {
    int t = blockIdx.x * blockDim.x + threadIdx.x;
    if (t >= N * NH) return;
    const int n  = t >> 2;
    const int hh = t & 3;
    const unsigned* p = htb32 + (size_t)n * (HC / 2) + hh * (CH / 2);
    const float* ps = att_src + hh * CH;
    const float* pd = att_dst + hh * CH;
    float s = 0.f, d = 0.f;
#pragma unroll
    for (int i = 0; i < CH / 2; i += 2) {
        uint2 u = *(const uint2*)(p + i);
        float4 as = *(const float4*)(ps + 2 * i);
        float4 ad = *(const float4*)(pd + 2 * i);
        float v0 = bfu_lo(u.x), v1 = bfu_hi(u.x);
        float v2 = bfu_lo(u.y), v3 = bfu_hi(u.y);
        s += v0 * as.x + v1 * as.y + v2 * as.z + v3 * as.w;
        d += v0 * ad.x + v1 * ad.y + v2 * ad.z + v3 * ad.w;
    }
    a_s[t] = s;
    a_d[t] = d;
}

// ---------------------------------------------------------------------------
// CSR build — dst-partitioned (XCD-local atomics & stores).
// Partition p = blockIdx.x % NPART owns dst range [p*npp, (p+1)*npp).
// Each partition's blocks grid-stride the FULL edge list and commit only
// their own dsts: esrc/cursor lines are touched by one partition only.
// ---------------------------------------------------------------------------
__global__ void init_counts(int* __restrict__ counts, int N) {
    int i = blockIdx.x * blockDim.x + threadIdx.x;
    if (i < N) counts[i] = 1;   // self loop
}

__global__ __launch_bounds__(256) void hist_part(const int* __restrict__ dst,
                                                 int* __restrict__ counts,
                                                 int E, int npp) {
    const int part = blockIdx.x & (NPART - 1);
    const int lo = part * npp, hi = lo + npp;
    const int nblk = gridDim.x >> 3;
    const int bi   = blockIdx.x >> 3;
    const int stride = nblk * 256;
    for (int e = bi * 256 + threadIdx.x; e < E; e += stride) {
        const int d = dst[e];
        if (d >= lo && d < hi) atomicAdd(&counts[d], 1);
    }
}

__global__ __launch_bounds__(256) void scan1(const int* __restrict__ counts,
                                             int* __restrict__ row_start,
                                             int* __restrict__ blk_sums, int N) {
    __shared__ int sh[256];
    const int b = blockIdx.x, t = threadIdx.x;
    const int base = b * SCAN_ELEMS + t * 4;
    int v[4], s = 0;
#pragma unroll
    for (int i = 0; i < 4; ++i) {
        v[i] = (base + i < N) ? counts[base + i] : 0;
        s += v[i];
    }
    sh[t] = s;
    __syncthreads();
    for (int off = 1; off < 256; off <<= 1) {
        int x = (t >= off) ? sh[t - off] : 0;
        __syncthreads();
        sh[t] += x;
        __syncthreads();
    }
    int run = sh[t] - s;
#pragma unroll
    for (int i = 0; i < 4; ++i) {
        if (base + i < N) row_start[base + i] = run;
        run += v[i];
    }
    if (t == 255) blk_sums[b] = sh[255];
}

__global__ void scan2(int* __restrict__ blk_sums, int nb) {
    if (threadIdx.x == 0 && blockIdx.x == 0) {
        int acc = 0;
        for (int i = 0; i < nb; ++i) { int v = blk_sums[i]; blk_sums[i] = acc; acc += v; }
    }
}

__global__ void scan3(int* __restrict__ row_start, int* __restrict__ cursor,
                      const int* __restrict__ blk_sums, int N, int total) {
    int i = blockIdx.x * blockDim.x + threadIdx.x;
    if (i < N) {
        int v = row_start[i] + blk_sums[i / SCAN_ELEMS];
        row_start[i] = v;
        cursor[i] = v;
    }
    if (i == 0) row_start[N] = total;
}

__global__ __launch_bounds__(256) void scatter_part(
        const int* __restrict__ src, const int* __restrict__ dst,
        int* __restrict__ cursor, unsigned short* __restrict__ esrc,
        int E, int N, int npp) {
    const int part = blockIdx.x & (NPART - 1);
    const int lo = part * npp, hi = lo + npp;
    const int nblk = gridDim.x >> 3;
    const int bi   = blockIdx.x >> 3;
    const int stride = nblk * 256;
    const int T = E + N;
    for (int e = bi * 256 + threadIdx.x; e < T; e += stride) {
        const int s = (e < E) ? src[e] : (e - E);
        const int d = (e < E) ? dst[e] : (e - E);
        if (d >= lo && d < hi) {
            int pos = atomicAdd(&cursor[d], 1);
            esrc[pos] = (unsigned short)s;
        }
    }
}

// ---------------------------------------------------------------------------
// Node-centric edge exponentials + denominators, one thread per node.
// ---------------------------------------------------------------------------
__global__ void edge_exf_csr(const int* __restrict__ row_start,
                             const unsigned short* __restrict__ esrc,
                             const float4* __restrict__ a_s4,
                             const float4* __restrict__ a_d4,
                             float4* __restrict__ exf4,
                             float4* __restrict__ denom4, int N) {
    int n = blockIdx.x * blockDim.x + threadIdx.x;
    if (n >= N) return;
    const float4 ad = a_d4[n];
    const int rs = row_start[n], re = row_start[n + 1];
    float sx = 0.f, sy = 0.f, sz = 0.f, sw = 0.f;
    for (int j = rs; j < re; ++j) {
        const int s = esrc[j];
        const float4 as = a_s4[s];
        float4 r;
        r.x = sig_exp(as.x + ad.x);
        r.y = sig_exp(as.y + ad.y);
        r.z = sig_exp(as.z + ad.z);
        r.w = sig_exp(as.w + ad.w);
        exf4[j] = r;
        sx += r.x; sy += r.y; sz += r.z; sw += r.w;
    }
    denom4[n] = make_float4(sx, sy, sz, sw);
}

// ---------------------------------------------------------------------------
// Weighted aggregation, one wave per dst node (pure FMA loop).
// ---------------------------------------------------------------------------
__global__ __launch_bounds__(256) void aggregate_csr(
        const int* __restrict__ row_start,
        const unsigned short* __restrict__ esrc,
        const float* __restrict__ exf,
        const float* __restrict__ denom,
        const unsigned* __restrict__ htb32, const float* __restrict__ bias,
        float* __restrict__ out, int N) {
    const int n = blockIdx.x * 4 + (threadIdx.x >> 6);
    if (n >= N) return;
    const int lane = threadIdx.x & 63;
    const int hh   = lane >> 4;
    const int c2   = lane * 2;

    const int rs = row_start[n], re = row_start[n + 1];
    const float inv = 1.0f / denom[n * NH + hh];

    float ax0 = 0.f, ay0 = 0.f;
    float ax1 = 0.f, ay1 = 0.f;
    int j = rs;
    for (; j + 1 < re; j += 2) {
        const int s0 = esrc[j], s1 = esrc[j + 1];
        const float e0 = exf[(size_t)j * NH + hh];
        const float e1 = exf[(size_t)(j + 1) * NH + hh];
        const unsigned u0 = htb32[(size_t)s0 * (HC / 2) + lane];
        const unsigned u1 = htb32[(size_t)s1 * (HC / 2) + lane];
        ax0 += e0 * bfu_lo(u0);  ay0 += e0 * bfu_hi(u0);
        ax1 += e1 * bfu_lo(u1);  ay1 += e1 * bfu_hi(u1);
    }
    if (j < re) {
        const int s0 = esrc[j];
        const float e0 = exf[(size_t)j * NH + hh];
        const unsigned u0 = htb32[(size_t)s0 * (HC / 2) + lane];
        ax0 += e0 * bfu_lo(u0);  ay0 += e0 * bfu_hi(u0);
    }
    float* op = out + (size_t)n * HC + c2;
    op[0] = (ax0 + ax1) * inv + bias[c2];
    op[1] = (ay0 + ay1) * inv + bias[c2 + 1];
}

// ---------------------------------------------------------------------------
extern "C" void kernel_launch(void* const* d_in, const int* in_sizes, int n_in,
                              void* d_out, int out_size, void* d_ws, size_t ws_size,
                              hipStream_t stream) {
    const float* h       = (const float*)d_in[0];
    const int*   src     = (const int*)d_in[1];
    const int*   dst     = (const int*)d_in[2];
    const float* W       = (const float*)d_in[3];
    const float* att_src = (const float*)d_in[4];
    const float* att_dst = (const float*)d_in[5];
    const float* bias    = (const float*)d_in[6];
    float*       out     = (float*)d_out;

    const int N = in_sizes[0] / IN_F;   // 50000
    const int E = in_sizes[1];          // 800000
    const int TOT = E + N;
    const int Mpad = (N + 63) & ~63;
    const int npp  = (N + NPART - 1) / NPART;   // nodes per partition

    // Workspace layout:
    // htb[N*128] bf16 | a_s[N*4] f32 | a_d[N*4] f32 | denom[N*4] f32 | cnt[N]
    // | row_start[N+1] | blk_sums[64] | pad | esrc[TOT] u16 | pad
    // | exf[TOT*4] f32 | Wt[128*512] bf16
    unsigned short* htb = (unsigned short*)d_ws;
    float* a_s   = (float*)(htb + (size_t)N * HC);
    float* a_d   = a_s + (size_t)N * NH;
    float* denom = a_d + (size_t)N * NH;
    int*   cnt   = (int*)(denom + (size_t)N * NH);
    int*   row_start = cnt + N;
    int*   blk_sums  = row_start + (N + 1);
    size_t off = ((size_t)((char*)(blk_sums + 64) - (char*)d_ws) + 15) & ~(size_t)15;
    unsigned short* esrc = (unsigned short*)((char*)d_ws + off);
    size_t off2 = ((size_t)((char*)(esrc + TOT) - (char*)d_ws) + 15) & ~(size_t)15;
    float* exf = (float*)((char*)d_ws + off2);
    unsigned short* Wt = (unsigned short*)(exf + (size_t)TOT * NH);

    const int nb = (N + SCAN_ELEMS - 1) / SCAN_ELEMS;

    // --- CSR build (dst-partitioned atomics/stores) ---
    init_counts<<<(N + 255) / 256, 256, 0, stream>>>(cnt, N);
    hist_part<<<2048, 256, 0, stream>>>(dst, cnt, E, npp);
    scan1<<<nb, 256, 0, stream>>>(cnt, row_start, blk_sums, N);
    scan2<<<1, 64, 0, stream>>>(blk_sums, nb);
    scan3<<<(N + 255) / 256, 256, 0, stream>>>(row_start, cnt, blk_sums, N, TOT);
    scatter_part<<<2048, 256, 0, stream>>>(src, dst, cnt, esrc, E, N, npp);

    // --- node transform (MFMA, f32 A staged direct, bf16 out) ---
    prep_w<<<(IN_F * HC + 255) / 256, 256, 0, stream>>>(W, Wt);
    gemm_f32a<<<Mpad / 64, 256, 0, stream>>>(h, Wt, htb, N);
    node_logits<<<(N * NH + 255) / 256, 256, 0, stream>>>((const unsigned*)htb,
                                                          att_src, att_dst,
                                                          a_s, a_d, N);

    // --- edge exponentials + denominators in CSR order ---
    edge_exf_csr<<<(N + 255) / 256, 256, 0, stream>>>(row_start, esrc,
                                                      (const float4*)a_s,
                                                      (const float4*)a_d,
                                                      (float4*)exf,
                                                      (float4*)denom, N);

    // --- weighted aggregation ---
    aggregate_csr<<<(N + 3) / 4, 256, 0, stream>>>(row_start, esrc, exf, denom,
                                                   (const unsigned*)htb, bias,
                                                   out, N);
}